// Round 3
// baseline (118.997 us; speedup 1.0000x reference)
//
#include <hip/hip_runtime.h>

#define IMH 1024
#define IMW 1024
#define GD 8
#define GH 16
#define GW 16
#define NC 12
#define ROWS 4

// LDS layout sG[buf][x][z][c]: x-stride 96 floats (0 mod 32 banks), z-stride 12.
// Gather bank = (12z + 4i) mod 32 -> the 8 z values hit 8 disjoint 4-bank
// groups covering all 32 banks; pixel mapping x = tid + 256p keeps each wave
// in one 64-aligned span -> <=2 distinct ix -> <=2-way conflicts (free, m136).
__global__ __launch_bounds__(256) void bsa_kernel(
    const float* __restrict__ grid,
    const float* __restrict__ guide,
    const float* __restrict__ image,
    float* __restrict__ out)
{
    const int y0  = blockIdx.x * ROWS;
    const int b   = blockIdx.y;
    const int tid = threadIdx.x;

    __shared__ __align__(16) float sG[2][GW][GD][NC];   // 12 KB double buffer
    float* const sbase_ptr = &sG[0][0][0][0];
    const int SBUF = GW * GD * NC;                      // 1536 floats

    const float* gb = grid + (size_t)b * NC * GD * GH * GW;

    // ---- hoisted per-thread staging indices (1536 vals / 256 thr = 6 each)
    int gsrc[6];   // offset into gb (minus the iy*GW term)
    int soff[6];   // offset into sG buffer
    #pragma unroll
    for (int k = 0; k < 6; ++k) {
        const int i = tid + 256 * k;
        const int x = i & (GW - 1);
        const int z = (i >> 4) & (GD - 1);
        const int c = i >> 7;
        gsrc[k] = ((c * GD + z) * GH) * GW + x;
        soff[k] = (x * GD + z) * NC + c;
    }

    // ---- hoisted per-thread x-interp quantities (constant across rows)
    int   ix0v[4], ix1v[4];
    float txv[4];
    #pragma unroll
    for (int p = 0; p < 4; ++p) {
        const int   x   = tid + 256 * p;
        const float gx  = (x + 0.5f) * ((float)GW / IMW);
        const float fxf = floorf(gx - 0.5f);
        txv[p]  = gx - 0.5f - fxf;
        const int fx = (int)fxf;
        ix0v[p] = min(GW - 1, max(0, fx));
        ix1v[p] = min(GW - 1, max(0, fx + 1));
    }

    // ---- stage row y0 into buffer 0
    {
        const float gy  = (y0 + 0.5f) * ((float)GH / IMH);
        const float fyf = floorf(gy - 0.5f);
        const float ty  = gy - 0.5f - fyf;
        const int   fy  = (int)fyf;
        const int   iy0 = min(GH - 1, max(0, fy));
        const int   iy1 = min(GH - 1, max(0, fy + 1));
        #pragma unroll
        for (int k = 0; k < 6; ++k) {
            const float v0 = gb[gsrc[k] + iy0 * GW];
            const float v1 = gb[gsrc[k] + iy1 * GW];
            sbase_ptr[soff[k]] = v0 + ty * (v1 - v0);
        }
    }
    __syncthreads();

    const size_t plane = (size_t)IMH * IMW;

    #pragma unroll
    for (int j = 0; j < ROWS; ++j) {
        // -- issue raw staging loads for row j+1 (in flight during compute)
        float nv0[6], nv1[6], nty = 0.0f;
        if (j + 1 < ROWS) {
            const int   yn  = y0 + j + 1;
            const float gy  = (yn + 0.5f) * ((float)GH / IMH);
            const float fyf = floorf(gy - 0.5f);
            nty = gy - 0.5f - fyf;
            const int fy  = (int)fyf;
            const int iy0 = min(GH - 1, max(0, fy));
            const int iy1 = min(GH - 1, max(0, fy + 1));
            #pragma unroll
            for (int k = 0; k < 6; ++k) {
                nv0[k] = gb[gsrc[k] + iy0 * GW];
                nv1[k] = gb[gsrc[k] + iy1 * GW];
            }
        }

        // -- compute row j
        const int y = y0 + j;
        const float* gp = guide + ((size_t)b * IMH + y) * IMW;
        const float* ip = image + ((size_t)b * 3 * IMH + y) * IMW;
        float*       op = out   + ((size_t)b * 3 * IMH + y) * IMW;
        const float* S  = sbase_ptr + (j & 1) * SBUF;

        #pragma unroll
        for (int p = 0; p < 4; ++p) {
            const int x = tid + 256 * p;

            const float gv = gp[x];
            const float rv = ip[x];
            const float g2 = ip[x + plane];
            const float bv = ip[x + 2 * plane];

            const float gz  = gv * (float)GD;
            const float fzf = floorf(gz - 0.5f);
            const float tz  = gz - 0.5f - fzf;
            const int   fzi = (int)fzf;
            const int   iz0 = min(GD - 1, max(0, fzi));
            const int   iz1 = min(GD - 1, max(0, fzi + 1));

            const float tx  = txv[p];
            const float w00 = (1.0f - tz) * (1.0f - tx);
            const float w01 = (1.0f - tz) * tx;
            const float w10 = tz * (1.0f - tx);
            const float w11 = tz * tx;

            const float* p00 = S + (ix0v[p] * GD + iz0) * NC;
            const float* p01 = S + (ix1v[p] * GD + iz0) * NC;
            const float* p10 = S + (ix0v[p] * GD + iz1) * NC;
            const float* p11 = S + (ix1v[p] * GD + iz1) * NC;

            float res[3];
            #pragma unroll
            for (int i = 0; i < 3; ++i) {
                const float4 a = *(const float4*)(p00 + 4 * i);
                const float4 c = *(const float4*)(p01 + 4 * i);
                const float4 d = *(const float4*)(p10 + 4 * i);
                const float4 e = *(const float4*)(p11 + 4 * i);
                const float c0 = w00 * a.x + w01 * c.x + w10 * d.x + w11 * e.x;
                const float c1 = w00 * a.y + w01 * c.y + w10 * d.y + w11 * e.y;
                const float c2 = w00 * a.z + w01 * c.z + w10 * d.z + w11 * e.z;
                const float c3 = w00 * a.w + w01 * c.w + w10 * d.w + w11 * e.w;
                res[i] = c0 * rv + c1 * g2 + c2 * bv + c3;
            }

            op[x]             = res[0];
            op[x + plane]     = res[1];
            op[x + 2 * plane] = res[2];
        }

        // -- finish staging row j+1 into the other buffer
        if (j + 1 < ROWS) {
            float* D = sbase_ptr + ((j + 1) & 1) * SBUF;
            #pragma unroll
            for (int k = 0; k < 6; ++k)
                D[soff[k]] = nv0[k] + nty * (nv1[k] - nv0[k]);
        }
        __syncthreads();
    }
}

extern "C" void kernel_launch(void* const* d_in, const int* in_sizes, int n_in,
                              void* d_out, int out_size, void* d_ws, size_t ws_size,
                              hipStream_t stream) {
    const float* grid  = (const float*)d_in[0];
    const float* guide = (const float*)d_in[1];
    const float* image = (const float*)d_in[2];
    float* out = (float*)d_out;

    const int B = in_sizes[1] / (IMH * IMW);   // guide is (B, H, W)
    dim3 g(IMH / ROWS, B);
    bsa_kernel<<<g, 256, 0, stream>>>(grid, guide, image, out);
}